// Round 3
// baseline (154.514 us; speedup 1.0000x reference)
//
#include <hip/hip_runtime.h>
#include <hip/hip_cooperative_groups.h>

namespace cg = cooperative_groups;

#define EPS 1e-5f

static __device__ const int OFFS[8] = {0, 100000, 150000, 151000, 151500, 151600, 151650, 151670};

// One cooperative kernel. 256 blocks x 256 threads; each block owns 8 batch rows.
// z1 (8x256) and z2 (8x128) live in registers across grid syncs; only BN partial
// sums + scale/shift go through global ws.
//
// ws layout: p1g[256][2][256], s1g[2][256], p2g[256][2][128], s2g[2][128]
__global__ __launch_bounds__(256) void deepfm_fused(
    const int* __restrict__ x, const float* __restrict__ emb,
    const float* __restrict__ wlin, const float* __restrict__ blin,
    const float* __restrict__ W1, const float* __restrict__ b1,
    const float* __restrict__ g1, const float* __restrict__ be1,
    const float* __restrict__ W2, const float* __restrict__ b2,
    const float* __restrict__ g2, const float* __restrict__ be2,
    const float* __restrict__ W3, const float* __restrict__ b3,
    float* __restrict__ p1g, float* __restrict__ s1g,
    float* __restrict__ p2g, float* __restrict__ s2g,
    float* __restrict__ out)
{
    cg::grid_group grid = cg::this_grid();

    __shared__ __align__(16) float h0s[8][128];
    __shared__ __align__(16) float h1s[8][256];
    __shared__ __align__(16) float redA[8][256];
    __shared__ __align__(16) float redB[8][256];
    __shared__ __align__(16) float wsS[4][4], wsQ[4][4];
    __shared__ float yfmS[8];

    const int t = threadIdx.x, blk = blockIdx.x;
    const int rp = t >> 5, l = t & 31;        // row-in-block, lane-in-32-group
    const int row = blk * 8 + rp;

    // ================= phase 0: gather + FM =================
    {
        const int f = l >> 2, dq = (l & 3) * 4;
        const int idxf = x[row * 8 + f];
        float4 e = *(const float4*)&emb[(size_t)(idxf + OFFS[f]) * 16 + dq];
        *(float4*)&h0s[rp][f * 16 + dq] = e;

        float4 s = e;
        float4 q = make_float4(e.x * e.x, e.y * e.y, e.z * e.z, e.w * e.w);
#pragma unroll
        for (int m = 4; m <= 16; m <<= 1) {
            s.x += __shfl_xor(s.x, m); s.y += __shfl_xor(s.y, m);
            s.z += __shfl_xor(s.z, m); s.w += __shfl_xor(s.w, m);
            q.x += __shfl_xor(q.x, m); q.y += __shfl_xor(q.y, m);
            q.z += __shfl_xor(q.z, m); q.w += __shfl_xor(q.w, m);
        }
        float pair = (s.x * s.x - q.x) + (s.y * s.y - q.y)
                   + (s.z * s.z - q.z) + (s.w * s.w - q.w);
        pair += __shfl_xor(pair, 1);
        pair += __shfl_xor(pair, 2);

        float lin = 0.f;
        if (l < 8) {
            int ids[8];
#pragma unroll
            for (int f2 = 0; f2 < 8; ++f2) ids[f2] = x[row * 8 + f2];
            bool dup = false;
            for (int g = 0; g < l; ++g) dup = dup || (ids[g] == ids[l]);
            lin = dup ? 0.f : wlin[ids[l]];
        }
        lin += __shfl_xor(lin, 1);
        lin += __shfl_xor(lin, 2);
        lin += __shfl_xor(lin, 4);
        if (l == 0) yfmS[rp] = 0.5f * pair + lin + blin[0];
    }
    __syncthreads();

    // ================= phase 1: GEMM1 (8x128 @ 128x256) =================
    // thread (rp,l): row rp, cols l*8 .. l*8+8 ; z1 kept in registers
    float z1r[8];
    {
        float acc[8] = {0.f, 0.f, 0.f, 0.f, 0.f, 0.f, 0.f, 0.f};
        const float* Wb = W1 + l * 8;
        for (int k = 0; k < 128; k += 4) {
            float4 h4 = *(const float4*)&h0s[rp][k];
            const float h_[4] = {h4.x, h4.y, h4.z, h4.w};
#pragma unroll
            for (int kk = 0; kk < 4; ++kk) {
                float4 wA = *(const float4*)&Wb[(k + kk) * 256];
                float4 wB = *(const float4*)&Wb[(k + kk) * 256 + 4];
                acc[0] += h_[kk] * wA.x; acc[1] += h_[kk] * wA.y;
                acc[2] += h_[kk] * wA.z; acc[3] += h_[kk] * wA.w;
                acc[4] += h_[kk] * wB.x; acc[5] += h_[kk] * wB.y;
                acc[6] += h_[kk] * wB.z; acc[7] += h_[kk] * wB.w;
            }
        }
        float4 bA = *(const float4*)&b1[l * 8];
        float4 bB = *(const float4*)&b1[l * 8 + 4];
        z1r[0] = acc[0] + bA.x; z1r[1] = acc[1] + bA.y;
        z1r[2] = acc[2] + bA.z; z1r[3] = acc[3] + bA.w;
        z1r[4] = acc[4] + bB.x; z1r[5] = acc[5] + bB.y;
        z1r[6] = acc[6] + bB.z; z1r[7] = acc[7] + bB.w;

        *(float4*)&redA[rp][l * 8]     = make_float4(z1r[0], z1r[1], z1r[2], z1r[3]);
        *(float4*)&redA[rp][l * 8 + 4] = make_float4(z1r[4], z1r[5], z1r[6], z1r[7]);
        *(float4*)&redB[rp][l * 8]     = make_float4(z1r[0]*z1r[0], z1r[1]*z1r[1], z1r[2]*z1r[2], z1r[3]*z1r[3]);
        *(float4*)&redB[rp][l * 8 + 4] = make_float4(z1r[4]*z1r[4], z1r[5]*z1r[5], z1r[6]*z1r[6], z1r[7]*z1r[7]);
    }
    __syncthreads();
    {
        float s = 0.f, q = 0.f;
#pragma unroll
        for (int r = 0; r < 8; ++r) { s += redA[r][t]; q += redB[r][t]; }
        p1g[blk * 512 + t] = s;
        p1g[blk * 512 + 256 + t] = q;
    }

    grid.sync();   // ---- sync 1: p1 partials visible ----

    // ================= phase 2: BN1 stats (blocks 0..63, 4 cols each) ======
    if (blk < 64) {
        float4 sA = *(const float4*)&p1g[t * 512 + blk * 4];
        float4 sB = *(const float4*)&p1g[t * 512 + 256 + blk * 4];
#pragma unroll
        for (int m = 1; m <= 32; m <<= 1) {
            sA.x += __shfl_xor(sA.x, m); sA.y += __shfl_xor(sA.y, m);
            sA.z += __shfl_xor(sA.z, m); sA.w += __shfl_xor(sA.w, m);
            sB.x += __shfl_xor(sB.x, m); sB.y += __shfl_xor(sB.y, m);
            sB.z += __shfl_xor(sB.z, m); sB.w += __shfl_xor(sB.w, m);
        }
        if ((t & 63) == 0) {
            const int w = t >> 6;
            *(float4*)&wsS[w][0] = sA;
            *(float4*)&wsQ[w][0] = sB;
        }
        __syncthreads();
        if (t < 4) {
            const int c = blk * 4 + t;
            float s = wsS[0][t] + wsS[1][t] + wsS[2][t] + wsS[3][t];
            float q = wsQ[0][t] + wsQ[1][t] + wsQ[2][t] + wsQ[3][t];
            float mean = s * (1.f / 2048.f);
            float var  = q * (1.f / 2048.f) - mean * mean;
            float sc = g1[c] * __frsqrt_rn(var + EPS);
            s1g[c] = sc;
            s1g[256 + c] = be1[c] - mean * sc;
        }
    }

    grid.sync();   // ---- sync 2: BN1 scale/shift visible ----

    // ================= phase 3: BN1+ReLU -> h1s, GEMM2 =================
    {
        float4 scA = *(const float4*)&s1g[l * 8];
        float4 scB = *(const float4*)&s1g[l * 8 + 4];
        float4 shA = *(const float4*)&s1g[256 + l * 8];
        float4 shB = *(const float4*)&s1g[256 + l * 8 + 4];
        float4 hA, hB;
        hA.x = fmaxf(z1r[0] * scA.x + shA.x, 0.f);
        hA.y = fmaxf(z1r[1] * scA.y + shA.y, 0.f);
        hA.z = fmaxf(z1r[2] * scA.z + shA.z, 0.f);
        hA.w = fmaxf(z1r[3] * scA.w + shA.w, 0.f);
        hB.x = fmaxf(z1r[4] * scB.x + shB.x, 0.f);
        hB.y = fmaxf(z1r[5] * scB.y + shB.y, 0.f);
        hB.z = fmaxf(z1r[6] * scB.z + shB.z, 0.f);
        hB.w = fmaxf(z1r[7] * scB.w + shB.w, 0.f);
        *(float4*)&h1s[rp][l * 8] = hA;
        *(float4*)&h1s[rp][l * 8 + 4] = hB;
    }
    __syncthreads();

    // thread (rp,l): row rp, cols l*4 .. l*4+4 of z2; kept in registers
    float z2r[4];
    {
        float acc[4] = {0.f, 0.f, 0.f, 0.f};
        const float* Wb = W2 + l * 4;
        for (int k = 0; k < 256; k += 4) {
            float4 h4 = *(const float4*)&h1s[rp][k];
            const float h_[4] = {h4.x, h4.y, h4.z, h4.w};
#pragma unroll
            for (int kk = 0; kk < 4; ++kk) {
                float4 w = *(const float4*)&Wb[(k + kk) * 128];
                acc[0] += h_[kk] * w.x; acc[1] += h_[kk] * w.y;
                acc[2] += h_[kk] * w.z; acc[3] += h_[kk] * w.w;
            }
        }
        float4 b4 = *(const float4*)&b2[l * 4];
        z2r[0] = acc[0] + b4.x; z2r[1] = acc[1] + b4.y;
        z2r[2] = acc[2] + b4.z; z2r[3] = acc[3] + b4.w;
    }
    __syncthreads();   // redA/redB reuse
    *(float4*)&redA[rp][l * 4] = make_float4(z2r[0], z2r[1], z2r[2], z2r[3]);
    *(float4*)&redB[rp][l * 4] = make_float4(z2r[0]*z2r[0], z2r[1]*z2r[1], z2r[2]*z2r[2], z2r[3]*z2r[3]);
    __syncthreads();
    if (t < 128) {
        float s = 0.f, q = 0.f;
#pragma unroll
        for (int r = 0; r < 8; ++r) { s += redA[r][t]; q += redB[r][t]; }
        p2g[blk * 256 + t] = s;
        p2g[blk * 256 + 128 + t] = q;
    }

    grid.sync();   // ---- sync 3: p2 partials visible ----

    // ================= phase 4: BN2 stats (blocks 0..31, 4 cols each) ======
    if (blk < 32) {
        float4 sA = *(const float4*)&p2g[t * 256 + blk * 4];
        float4 sB = *(const float4*)&p2g[t * 256 + 128 + blk * 4];
#pragma unroll
        for (int m = 1; m <= 32; m <<= 1) {
            sA.x += __shfl_xor(sA.x, m); sA.y += __shfl_xor(sA.y, m);
            sA.z += __shfl_xor(sA.z, m); sA.w += __shfl_xor(sA.w, m);
            sB.x += __shfl_xor(sB.x, m); sB.y += __shfl_xor(sB.y, m);
            sB.z += __shfl_xor(sB.z, m); sB.w += __shfl_xor(sB.w, m);
        }
        if ((t & 63) == 0) {
            const int w = t >> 6;
            *(float4*)&wsS[w][0] = sA;
            *(float4*)&wsQ[w][0] = sB;
        }
        __syncthreads();
        if (t < 4) {
            const int c = blk * 4 + t;
            float s = wsS[0][t] + wsS[1][t] + wsS[2][t] + wsS[3][t];
            float q = wsQ[0][t] + wsQ[1][t] + wsQ[2][t] + wsQ[3][t];
            float mean = s * (1.f / 2048.f);
            float var  = q * (1.f / 2048.f) - mean * mean;
            float sc = g2[c] * __frsqrt_rn(var + EPS);
            s2g[c] = sc;
            s2g[128 + c] = be2[c] - mean * sc;
        }
    }

    grid.sync();   // ---- sync 4: BN2 scale/shift visible ----

    // ================= phase 5: BN2+ReLU, dot W3, output =================
    {
        float4 sc = *(const float4*)&s2g[l * 4];
        float4 sh = *(const float4*)&s2g[128 + l * 4];
        float4 w3 = *(const float4*)&W3[l * 4];
        float acc = fmaxf(z2r[0] * sc.x + sh.x, 0.f) * w3.x
                  + fmaxf(z2r[1] * sc.y + sh.y, 0.f) * w3.y
                  + fmaxf(z2r[2] * sc.z + sh.z, 0.f) * w3.z
                  + fmaxf(z2r[3] * sc.w + sh.w, 0.f) * w3.w;
#pragma unroll
        for (int m = 16; m >= 1; m >>= 1) acc += __shfl_xor(acc, m);
        if (l == 0) out[row] = acc + b3[0] + yfmS[rp];
    }
}

extern "C" void kernel_launch(void* const* d_in, const int* in_sizes, int n_in,
                              void* d_out, int out_size, void* d_ws, size_t ws_size,
                              hipStream_t stream) {
    const int*   x    = (const int*)d_in[0];
    const float* emb  = (const float*)d_in[1];
    const float* wlin = (const float*)d_in[2];
    const float* blin = (const float*)d_in[3];
    const float* W1   = (const float*)d_in[4];
    const float* b1   = (const float*)d_in[5];
    const float* g1   = (const float*)d_in[6];
    const float* be1  = (const float*)d_in[7];
    const float* W2   = (const float*)d_in[8];
    const float* b2   = (const float*)d_in[9];
    const float* g2   = (const float*)d_in[10];
    const float* be2  = (const float*)d_in[11];
    const float* W3   = (const float*)d_in[12];
    const float* b3   = (const float*)d_in[13];

    float* ws  = (float*)d_ws;
    float* p1g = ws;                    // 256*512
    float* s1g = p1g + 256 * 512;       // 512
    float* p2g = s1g + 512;             // 256*256
    float* s2g = p2g + 256 * 256;       // 256
    float* out = (float*)d_out;

    void* args[] = {
        (void*)&x, (void*)&emb, (void*)&wlin, (void*)&blin,
        (void*)&W1, (void*)&b1, (void*)&g1, (void*)&be1,
        (void*)&W2, (void*)&b2, (void*)&g2, (void*)&be2,
        (void*)&W3, (void*)&b3,
        (void*)&p1g, (void*)&s1g, (void*)&p2g, (void*)&s2g, (void*)&out
    };
    hipLaunchCooperativeKernel((void*)deepfm_fused, dim3(256), dim3(256),
                               args, 0, stream);
}

// Round 4
// 79.576 us; speedup vs baseline: 1.9417x; 1.9417x over previous
//
#include <hip/hip_runtime.h>

#define EPS 1e-5f

static __device__ const int OFFS[8] = {0, 100000, 150000, 151000, 151500, 151600, 151650, 151670};

// ---- coherent-point 8B accesses (bypass non-coherent per-XCD L2) ----
__device__ __forceinline__ void st_f2(float* p, float a, float b) {
    union { float f[2]; unsigned long long u; } v;
    v.f[0] = a; v.f[1] = b;
    __hip_atomic_store((unsigned long long*)p, v.u, __ATOMIC_RELAXED, __HIP_MEMORY_SCOPE_AGENT);
}
__device__ __forceinline__ float2 ld_f2(const float* p) {
    union { unsigned long long u; float f[2]; } v;
    v.u = __hip_atomic_load((const unsigned long long*)p, __ATOMIC_RELAXED, __HIP_MEMORY_SCOPE_AGENT);
    return make_float2(v.f[0], v.f[1]);
}

// Hand-rolled grid barrier: 4 counters x 64 arrivals. Prior __syncthreads drains
// vmcnt (all this block's agent-scope stores retired -> visible at coherent point)
// before the arrival add. Spinners use relaxed agent loads.
#define GBAR(ph)  do {                                                                     \
    __syncthreads();                                                                       \
    if (t == 0)                                                                            \
        __hip_atomic_fetch_add(&cnt[(ph)*4 + (blk & 3)], 1u,                               \
                               __ATOMIC_RELAXED, __HIP_MEMORY_SCOPE_AGENT);                \
    if (t < 4) {                                                                           \
        while (__hip_atomic_load(&cnt[(ph)*4 + t],                                         \
                                 __ATOMIC_RELAXED, __HIP_MEMORY_SCOPE_AGENT) < 64u)        \
            __builtin_amdgcn_s_sleep(2);                                                   \
    }                                                                                      \
    __syncthreads();                                                                       \
} while (0)

// 256 blocks x 512 threads; block owns 8 batch rows (wave r = row r).
// z1 (4/thread) and z2 (2/thread) live in registers across barriers.
__global__ __launch_bounds__(512, 2) void deepfm_one(
    const int* __restrict__ x, const float* __restrict__ emb,
    const float* __restrict__ wlin, const float* __restrict__ blin,
    const float* __restrict__ W1, const float* __restrict__ b1,
    const float* __restrict__ g1, const float* __restrict__ be1,
    const float* __restrict__ W2, const float* __restrict__ b2,
    const float* __restrict__ g2, const float* __restrict__ be2,
    const float* __restrict__ W3, const float* __restrict__ b3,
    unsigned int* __restrict__ cnt,
    float* __restrict__ p1g, float* __restrict__ s1g,
    float* __restrict__ p2g, float* __restrict__ s2g,
    float* __restrict__ out)
{
    __shared__ __align__(16) float h0s[8][128];
    __shared__ __align__(16) float h1s[8][256];
    __shared__ __align__(16) float redA[8][256];
    __shared__ __align__(16) float redB[8][256];
    __shared__ float yfmS[8];

    const int t = threadIdx.x, blk = blockIdx.x;
    const int r = t >> 6, c = t & 63;     // wave r owns row r; lane c
    const int row = blk * 8 + r;

    // ========== phase 0: gather + FM ==========
    {
        const int f = c >> 3, dp = c & 7;
        const int idxf = x[row * 8 + f];
        float2 e = *(const float2*)&emb[(size_t)(idxf + OFFS[f]) * 16 + dp * 2];
        *(float2*)&h0s[r][f * 16 + dp * 2] = e;

        float sx = e.x, sy = e.y, qx = e.x * e.x, qy = e.y * e.y;
#pragma unroll
        for (int m = 8; m <= 32; m <<= 1) {
            sx += __shfl_xor(sx, m); sy += __shfl_xor(sy, m);
            qx += __shfl_xor(qx, m); qy += __shfl_xor(qy, m);
        }
        float pair = (sx * sx - qx) + (sy * sy - qy);
        pair += __shfl_xor(pair, 1);
        pair += __shfl_xor(pair, 2);
        pair += __shfl_xor(pair, 4);

        float lin = 0.f;
        if (c < 8) {
            int ids[8];
#pragma unroll
            for (int g = 0; g < 8; ++g) ids[g] = x[row * 8 + g];
            bool dup = false;
            for (int g = 0; g < c; ++g) dup = dup || (ids[g] == ids[c]);
            lin = dup ? 0.f : wlin[ids[c]];
        }
        lin += __shfl_xor(lin, 1);
        lin += __shfl_xor(lin, 2);
        lin += __shfl_xor(lin, 4);
        if (c == 0) yfmS[r] = 0.5f * pair + lin + blin[0];
    }
    __syncthreads();

    // ========== phase A: GEMM1 (8x128 @ 128x256), z1 in regs ==========
    float z1r0, z1r1, z1r2, z1r3;
    {
        const int j0 = c * 4;
        const float* W = W1 + j0;
        float a0 = 0.f, a1 = 0.f, a2 = 0.f, a3 = 0.f;
#pragma unroll 2
        for (int k = 0; k < 128; k += 4) {
            float4 h4 = *(const float4*)&h0s[r][k];
            float4 w0 = *(const float4*)&W[(k + 0) * 256];
            float4 w1 = *(const float4*)&W[(k + 1) * 256];
            float4 w2 = *(const float4*)&W[(k + 2) * 256];
            float4 w3v = *(const float4*)&W[(k + 3) * 256];
            a0 += h4.x * w0.x + h4.y * w1.x + h4.z * w2.x + h4.w * w3v.x;
            a1 += h4.x * w0.y + h4.y * w1.y + h4.z * w2.y + h4.w * w3v.y;
            a2 += h4.x * w0.z + h4.y * w1.z + h4.z * w2.z + h4.w * w3v.z;
            a3 += h4.x * w0.w + h4.y * w1.w + h4.z * w2.w + h4.w * w3v.w;
        }
        float4 b4 = *(const float4*)&b1[j0];
        z1r0 = a0 + b4.x; z1r1 = a1 + b4.y; z1r2 = a2 + b4.z; z1r3 = a3 + b4.w;
        *(float4*)&redA[r][j0] = make_float4(z1r0, z1r1, z1r2, z1r3);
        *(float4*)&redB[r][j0] = make_float4(z1r0 * z1r0, z1r1 * z1r1, z1r2 * z1r2, z1r3 * z1r3);
    }
    __syncthreads();
    if (t < 256) {
        float s = 0.f, q = 0.f;
#pragma unroll
        for (int rr = 0; rr < 8; ++rr) { s += redA[rr][t]; q += redB[rr][t]; }
        st_f2(&p1g[2 * (blk * 256 + t)], s, q);
    }
    GBAR(0);

    // ========== phase B: BN1 stats, blocks 0..63 x 4 cols ==========
    if (blk < 64 && t < 256) {
        const int col = blk * 4 + r;   // r in 0..3 here
        float s = 0.f, q = 0.f;
#pragma unroll
        for (int i = 0; i < 4; ++i) {
            float2 v = ld_f2(&p1g[2 * ((c + i * 64) * 256 + col)]);
            s += v.x; q += v.y;
        }
#pragma unroll
        for (int m = 1; m <= 32; m <<= 1) { s += __shfl_xor(s, m); q += __shfl_xor(q, m); }
        if (c == 0) {
            float mean = s * (1.f / 2048.f);
            float var  = q * (1.f / 2048.f) - mean * mean;
            float sc = g1[col] * __frsqrt_rn(var + EPS);
            st_f2(&s1g[2 * col], sc, be1[col] - mean * sc);
        }
    }
    GBAR(1);

    // ========== phase C: BN1+ReLU -> h1s, GEMM2, z2 in regs ==========
    {
        const int j0 = c * 4;
        float2 ss0 = ld_f2(&s1g[2 * (j0 + 0)]);
        float2 ss1 = ld_f2(&s1g[2 * (j0 + 1)]);
        float2 ss2 = ld_f2(&s1g[2 * (j0 + 2)]);
        float2 ss3 = ld_f2(&s1g[2 * (j0 + 3)]);
        float4 h;
        h.x = fmaxf(z1r0 * ss0.x + ss0.y, 0.f);
        h.y = fmaxf(z1r1 * ss1.x + ss1.y, 0.f);
        h.z = fmaxf(z1r2 * ss2.x + ss2.y, 0.f);
        h.w = fmaxf(z1r3 * ss3.x + ss3.y, 0.f);
        *(float4*)&h1s[r][j0] = h;
    }
    __syncthreads();

    float z2a, z2b;
    {
        const int j0 = c * 2;
        const float* W = W2 + j0;
        float a0 = 0.f, a1 = 0.f;
#pragma unroll 2
        for (int k = 0; k < 256; k += 4) {
            float4 h4 = *(const float4*)&h1s[r][k];
            float2 w0 = *(const float2*)&W[(k + 0) * 128];
            float2 w1 = *(const float2*)&W[(k + 1) * 128];
            float2 w2 = *(const float2*)&W[(k + 2) * 128];
            float2 w3v = *(const float2*)&W[(k + 3) * 128];
            a0 += h4.x * w0.x + h4.y * w1.x + h4.z * w2.x + h4.w * w3v.x;
            a1 += h4.x * w0.y + h4.y * w1.y + h4.z * w2.y + h4.w * w3v.y;
        }
        float2 b2v = *(const float2*)&b2[j0];
        z2a = a0 + b2v.x; z2b = a1 + b2v.y;
        *(float2*)&redA[r][j0] = make_float2(z2a, z2b);
        *(float2*)&redB[r][j0] = make_float2(z2a * z2a, z2b * z2b);
    }
    __syncthreads();
    if (t < 128) {
        float s = 0.f, q = 0.f;
#pragma unroll
        for (int rr = 0; rr < 8; ++rr) { s += redA[rr][t]; q += redB[rr][t]; }
        st_f2(&p2g[2 * (blk * 128 + t)], s, q);
    }
    GBAR(2);

    // ========== phase D: BN2 stats, blocks 0..31 x 4 cols ==========
    if (blk < 32 && t < 256) {
        const int col = blk * 4 + r;
        float s = 0.f, q = 0.f;
#pragma unroll
        for (int i = 0; i < 4; ++i) {
            float2 v = ld_f2(&p2g[2 * ((c + i * 64) * 128 + col)]);
            s += v.x; q += v.y;
        }
#pragma unroll
        for (int m = 1; m <= 32; m <<= 1) { s += __shfl_xor(s, m); q += __shfl_xor(q, m); }
        if (c == 0) {
            float mean = s * (1.f / 2048.f);
            float var  = q * (1.f / 2048.f) - mean * mean;
            float sc = g2[col] * __frsqrt_rn(var + EPS);
            st_f2(&s2g[2 * col], sc, be2[col] - mean * sc);
        }
    }
    GBAR(3);

    // ========== phase E: BN2+ReLU, dot W3, output ==========
    {
        const int j0 = c * 2;
        float2 sA = ld_f2(&s2g[2 * (j0 + 0)]);
        float2 sB = ld_f2(&s2g[2 * (j0 + 1)]);
        float2 w3 = *(const float2*)&W3[j0];
        float acc = fmaxf(z2a * sA.x + sA.y, 0.f) * w3.x
                  + fmaxf(z2b * sB.x + sB.y, 0.f) * w3.y;
#pragma unroll
        for (int m = 1; m <= 32; m <<= 1) acc += __shfl_xor(acc, m);
        if (c == 0) out[row] = acc + b3[0] + yfmS[r];
    }
}

extern "C" void kernel_launch(void* const* d_in, const int* in_sizes, int n_in,
                              void* d_out, int out_size, void* d_ws, size_t ws_size,
                              hipStream_t stream) {
    const int*   x    = (const int*)d_in[0];
    const float* emb  = (const float*)d_in[1];
    const float* wlin = (const float*)d_in[2];
    const float* blin = (const float*)d_in[3];
    const float* W1   = (const float*)d_in[4];
    const float* b1   = (const float*)d_in[5];
    const float* g1   = (const float*)d_in[6];
    const float* be1  = (const float*)d_in[7];
    const float* W2   = (const float*)d_in[8];
    const float* b2   = (const float*)d_in[9];
    const float* g2   = (const float*)d_in[10];
    const float* be2  = (const float*)d_in[11];
    const float* W3   = (const float*)d_in[12];
    const float* b3   = (const float*)d_in[13];

    unsigned int* cnt = (unsigned int*)d_ws;        // 16 uints (4 barriers x 4)
    float* p1g = (float*)d_ws + 16;                 // 256*256 float2
    float* s1g = p1g + 2 * 256 * 256;               // 256 float2
    float* p2g = s1g + 2 * 256;                     // 256*128 float2
    float* s2g = p2g + 2 * 256 * 128;               // 128 float2
    float* out = (float*)d_out;

    hipMemsetAsync(d_ws, 0, 64, stream);            // zero barrier counters

    void* args[] = {
        (void*)&x, (void*)&emb, (void*)&wlin, (void*)&blin,
        (void*)&W1, (void*)&b1, (void*)&g1, (void*)&be1,
        (void*)&W2, (void*)&b2, (void*)&g2, (void*)&be2,
        (void*)&W3, (void*)&b3,
        (void*)&cnt, (void*)&p1g, (void*)&s1g, (void*)&p2g, (void*)&s2g, (void*)&out
    };
    hipLaunchCooperativeKernel((void*)deepfm_one, dim3(256), dim3(512),
                               args, 0, stream);
}

// Round 5
// 53.200 us; speedup vs baseline: 2.9044x; 1.4958x over previous
//
#include <hip/hip_runtime.h>

#define EPS 1e-5f
#define NBLK 128

static __device__ const int OFFS[8] = {0, 100000, 150000, 151000, 151500, 151600, 151650, 151670};

// ---- coherent-point 8B accesses (bypass non-coherent per-XCD L2) ----
__device__ __forceinline__ void st_f2(float* p, float a, float b) {
    union { float f[2]; unsigned long long u; } v;
    v.f[0] = a; v.f[1] = b;
    __hip_atomic_store((unsigned long long*)p, v.u, __ATOMIC_RELAXED, __HIP_MEMORY_SCOPE_AGENT);
}
__device__ __forceinline__ float2 ld_f2(const float* p) {
    union { unsigned long long u; float f[2]; } v;
    v.u = __hip_atomic_load((const unsigned long long*)p, __ATOMIC_RELAXED, __HIP_MEMORY_SCOPE_AGENT);
    return make_float2(v.f[0], v.f[1]);
}

// Grid barrier: 4 counters x 32 arrivals; ONE poller per block (t==0) sums the
// 4 counters with s_sleep backoff. The __syncthreads before arrival drains each
// wave's vmcnt, so all agent-scope partial stores are at the coherent point
// before the arrival add (pattern validated in R4).
#define GBAR(ph) do {                                                                        \
    __syncthreads();                                                                         \
    if (t == 0) {                                                                            \
        __hip_atomic_fetch_add(&cnt[(ph)*4 + (blk & 3)], 1u,                                 \
                               __ATOMIC_RELAXED, __HIP_MEMORY_SCOPE_AGENT);                  \
        unsigned s;                                                                          \
        do {                                                                                 \
            s  = __hip_atomic_load(&cnt[(ph)*4+0], __ATOMIC_RELAXED, __HIP_MEMORY_SCOPE_AGENT); \
            s += __hip_atomic_load(&cnt[(ph)*4+1], __ATOMIC_RELAXED, __HIP_MEMORY_SCOPE_AGENT); \
            s += __hip_atomic_load(&cnt[(ph)*4+2], __ATOMIC_RELAXED, __HIP_MEMORY_SCOPE_AGENT); \
            s += __hip_atomic_load(&cnt[(ph)*4+3], __ATOMIC_RELAXED, __HIP_MEMORY_SCOPE_AGENT); \
            if (s >= NBLK) break;                                                            \
            __builtin_amdgcn_s_sleep(8);                                                     \
        } while (1);                                                                         \
    }                                                                                        \
    __syncthreads();                                                                         \
} while (0)

// 128 blocks x 512 threads; block owns 16 batch rows. z1 (8/thread) and z2
// (4/thread) live in registers across the 2 barriers. BN stats are reduced
// redundantly by every block after each barrier (no second sync needed).
__global__ __launch_bounds__(512) void deepfm_one(
    const int* __restrict__ x, const float* __restrict__ emb,
    const float* __restrict__ wlin, const float* __restrict__ blin,
    const float* __restrict__ W1, const float* __restrict__ b1,
    const float* __restrict__ g1, const float* __restrict__ be1,
    const float* __restrict__ W2, const float* __restrict__ b2,
    const float* __restrict__ g2, const float* __restrict__ be2,
    const float* __restrict__ W3, const float* __restrict__ b3,
    unsigned int* __restrict__ cnt,
    float* __restrict__ p1g, float* __restrict__ p2g,
    float* __restrict__ out)
{
    __shared__ __align__(16) float h0s[16][128];   // 8 KB
    __shared__ __align__(16) float h1s[16][256];   // 16 KB
    __shared__ __align__(16) float redS[16][256];  // 16 KB
    __shared__ __align__(16) float redQ[16][256];  // 16 KB
    __shared__ __align__(16) float sclS[256], shfS[256];
    __shared__ float yfmS[16];

    const int t = threadIdx.x, blk = blockIdx.x;
    const int r = t >> 5, l = t & 31;    // row-in-block (0..15), lane (0..31)
    const int row = blk * 16 + r;

    // ========== phase 0: gather + FM ==========
    {
        const int f = l >> 2, dq = (l & 3) * 4;
        const int idxf = x[row * 8 + f];
        float4 e = *(const float4*)&emb[(size_t)(idxf + OFFS[f]) * 16 + dq];
        *(float4*)&h0s[r][f * 16 + dq] = e;

        float4 s = e;
        float4 q = make_float4(e.x * e.x, e.y * e.y, e.z * e.z, e.w * e.w);
#pragma unroll
        for (int m = 4; m <= 16; m <<= 1) {
            s.x += __shfl_xor(s.x, m); s.y += __shfl_xor(s.y, m);
            s.z += __shfl_xor(s.z, m); s.w += __shfl_xor(s.w, m);
            q.x += __shfl_xor(q.x, m); q.y += __shfl_xor(q.y, m);
            q.z += __shfl_xor(q.z, m); q.w += __shfl_xor(q.w, m);
        }
        float pair = (s.x * s.x - q.x) + (s.y * s.y - q.y)
                   + (s.z * s.z - q.z) + (s.w * s.w - q.w);
        pair += __shfl_xor(pair, 1);
        pair += __shfl_xor(pair, 2);

        float lin = 0.f;
        if (l < 8) {
            int ids[8];
#pragma unroll
            for (int g = 0; g < 8; ++g) ids[g] = x[row * 8 + g];
            bool dup = false;
            for (int g = 0; g < l; ++g) dup = dup || (ids[g] == ids[l]);
            lin = dup ? 0.f : wlin[ids[l]];
        }
        lin += __shfl_xor(lin, 1);
        lin += __shfl_xor(lin, 2);
        lin += __shfl_xor(lin, 4);
        if (l == 0) yfmS[r] = 0.5f * pair + lin + blin[0];
    }
    __syncthreads();

    // ========== phase A: GEMM1 (16x128 @ 128x256), z1 in regs ==========
    float z1r[8];
    {
        const int j0 = l * 8;
        const float* W = W1 + j0;
        float a[8] = {0.f, 0.f, 0.f, 0.f, 0.f, 0.f, 0.f, 0.f};
#pragma unroll 2
        for (int k = 0; k < 128; k += 4) {
            float4 h4 = *(const float4*)&h0s[r][k];
            const float h_[4] = {h4.x, h4.y, h4.z, h4.w};
#pragma unroll
            for (int kk = 0; kk < 4; ++kk) {
                float4 wA = *(const float4*)&W[(k + kk) * 256];
                float4 wB = *(const float4*)&W[(k + kk) * 256 + 4];
                a[0] += h_[kk] * wA.x; a[1] += h_[kk] * wA.y;
                a[2] += h_[kk] * wA.z; a[3] += h_[kk] * wA.w;
                a[4] += h_[kk] * wB.x; a[5] += h_[kk] * wB.y;
                a[6] += h_[kk] * wB.z; a[7] += h_[kk] * wB.w;
            }
        }
        float4 bA = *(const float4*)&b1[j0];
        float4 bB = *(const float4*)&b1[j0 + 4];
        z1r[0] = a[0] + bA.x; z1r[1] = a[1] + bA.y;
        z1r[2] = a[2] + bA.z; z1r[3] = a[3] + bA.w;
        z1r[4] = a[4] + bB.x; z1r[5] = a[5] + bB.y;
        z1r[6] = a[6] + bB.z; z1r[7] = a[7] + bB.w;
        *(float4*)&redS[r][j0]     = make_float4(z1r[0], z1r[1], z1r[2], z1r[3]);
        *(float4*)&redS[r][j0 + 4] = make_float4(z1r[4], z1r[5], z1r[6], z1r[7]);
        *(float4*)&redQ[r][j0]     = make_float4(z1r[0]*z1r[0], z1r[1]*z1r[1], z1r[2]*z1r[2], z1r[3]*z1r[3]);
        *(float4*)&redQ[r][j0 + 4] = make_float4(z1r[4]*z1r[4], z1r[5]*z1r[5], z1r[6]*z1r[6], z1r[7]*z1r[7]);
    }
    __syncthreads();
    if (t < 256) {
        float s = 0.f, q = 0.f;
#pragma unroll
        for (int rr = 0; rr < 16; ++rr) { s += redS[rr][t]; q += redQ[rr][t]; }
        st_f2(&p1g[2 * (blk * 256 + t)], s, q);
    }
    GBAR(0);

    // ========== phase B: BN1 stats, redundant in every block ==========
    {
        const int col = t & 255, h = t >> 8;      // 2 threads/col, 64 partials each
        float s = 0.f, q = 0.f;
#pragma unroll 16
        for (int i = 0; i < 64; ++i) {
            float2 v = ld_f2(&p1g[2 * ((h * 64 + i) * 256 + col)]);
            s += v.x; q += v.y;
        }
        __syncthreads();                          // redS/redQ free for reuse
        redS[h][col] = s;
        redQ[h][col] = q;
    }
    __syncthreads();
    if (t < 256) {
        float s = redS[0][t] + redS[1][t];
        float q = redQ[0][t] + redQ[1][t];
        float mean = s * (1.f / 2048.f);
        float var  = q * (1.f / 2048.f) - mean * mean;
        float sc = g1[t] * __frsqrt_rn(var + EPS);
        sclS[t] = sc;
        shfS[t] = be1[t] - mean * sc;
    }
    __syncthreads();

    // ========== phase C: BN1+ReLU -> h1s, GEMM2, z2 in regs ==========
    {
        const int j0 = l * 8;
        float4 scA = *(const float4*)&sclS[j0], scB = *(const float4*)&sclS[j0 + 4];
        float4 shA = *(const float4*)&shfS[j0], shB = *(const float4*)&shfS[j0 + 4];
        float4 hA, hB;
        hA.x = fmaxf(z1r[0] * scA.x + shA.x, 0.f);
        hA.y = fmaxf(z1r[1] * scA.y + shA.y, 0.f);
        hA.z = fmaxf(z1r[2] * scA.z + shA.z, 0.f);
        hA.w = fmaxf(z1r[3] * scA.w + shA.w, 0.f);
        hB.x = fmaxf(z1r[4] * scB.x + shB.x, 0.f);
        hB.y = fmaxf(z1r[5] * scB.y + shB.y, 0.f);
        hB.z = fmaxf(z1r[6] * scB.z + shB.z, 0.f);
        hB.w = fmaxf(z1r[7] * scB.w + shB.w, 0.f);
        *(float4*)&h1s[r][j0] = hA;
        *(float4*)&h1s[r][j0 + 4] = hB;
    }
    __syncthreads();

    float z2r[4];
    {
        const int j0 = l * 4;
        const float* W = W2 + j0;
        float a[4] = {0.f, 0.f, 0.f, 0.f};
#pragma unroll 2
        for (int k = 0; k < 256; k += 4) {
            float4 h4 = *(const float4*)&h1s[r][k];
            const float h_[4] = {h4.x, h4.y, h4.z, h4.w};
#pragma unroll
            for (int kk = 0; kk < 4; ++kk) {
                float4 w = *(const float4*)&W[(k + kk) * 128];
                a[0] += h_[kk] * w.x; a[1] += h_[kk] * w.y;
                a[2] += h_[kk] * w.z; a[3] += h_[kk] * w.w;
            }
        }
        float4 b4 = *(const float4*)&b2[j0];
        z2r[0] = a[0] + b4.x; z2r[1] = a[1] + b4.y;
        z2r[2] = a[2] + b4.z; z2r[3] = a[3] + b4.w;
    }
    __syncthreads();                              // redS/redQ reuse
    {
        const int j0 = l * 4;
        *(float4*)&redS[r][j0] = make_float4(z2r[0], z2r[1], z2r[2], z2r[3]);
        *(float4*)&redQ[r][j0] = make_float4(z2r[0]*z2r[0], z2r[1]*z2r[1], z2r[2]*z2r[2], z2r[3]*z2r[3]);
    }
    __syncthreads();
    if (t < 128) {
        float s = 0.f, q = 0.f;
#pragma unroll
        for (int rr = 0; rr < 16; ++rr) { s += redS[rr][t]; q += redQ[rr][t]; }
        st_f2(&p2g[2 * (blk * 128 + t)], s, q);
    }
    GBAR(1);

    // ========== phase D: BN2 stats, redundant in every block ==========
    {
        const int col = t & 127, h = t >> 7;      // 4 threads/col, 32 partials each
        float s = 0.f, q = 0.f;
#pragma unroll 16
        for (int i = 0; i < 32; ++i) {
            float2 v = ld_f2(&p2g[2 * ((h * 32 + i) * 128 + col)]);
            s += v.x; q += v.y;
        }
        __syncthreads();
        redS[h][col] = s;
        redQ[h][col] = q;
    }
    __syncthreads();
    if (t < 128) {
        float s = redS[0][t] + redS[1][t] + redS[2][t] + redS[3][t];
        float q = redQ[0][t] + redQ[1][t] + redQ[2][t] + redQ[3][t];
        float mean = s * (1.f / 2048.f);
        float var  = q * (1.f / 2048.f) - mean * mean;
        float sc = g2[t] * __frsqrt_rn(var + EPS);
        sclS[t] = sc;
        shfS[t] = be2[t] - mean * sc;
    }
    __syncthreads();

    // ========== phase E: BN2+ReLU, dot W3, output ==========
    {
        const int j0 = l * 4;
        float4 sc = *(const float4*)&sclS[j0];
        float4 sh = *(const float4*)&shfS[j0];
        float4 w3 = *(const float4*)&W3[j0];
        float acc = fmaxf(z2r[0] * sc.x + sh.x, 0.f) * w3.x
                  + fmaxf(z2r[1] * sc.y + sh.y, 0.f) * w3.y
                  + fmaxf(z2r[2] * sc.z + sh.z, 0.f) * w3.z
                  + fmaxf(z2r[3] * sc.w + sh.w, 0.f) * w3.w;
#pragma unroll
        for (int m = 16; m >= 1; m >>= 1) acc += __shfl_xor(acc, m);
        if (l == 0) out[row] = acc + b3[0] + yfmS[r];
    }
}

extern "C" void kernel_launch(void* const* d_in, const int* in_sizes, int n_in,
                              void* d_out, int out_size, void* d_ws, size_t ws_size,
                              hipStream_t stream) {
    const int*   x    = (const int*)d_in[0];
    const float* emb  = (const float*)d_in[1];
    const float* wlin = (const float*)d_in[2];
    const float* blin = (const float*)d_in[3];
    const float* W1   = (const float*)d_in[4];
    const float* b1   = (const float*)d_in[5];
    const float* g1   = (const float*)d_in[6];
    const float* be1  = (const float*)d_in[7];
    const float* W2   = (const float*)d_in[8];
    const float* b2   = (const float*)d_in[9];
    const float* g2   = (const float*)d_in[10];
    const float* be2  = (const float*)d_in[11];
    const float* W3   = (const float*)d_in[12];
    const float* b3   = (const float*)d_in[13];

    unsigned int* cnt = (unsigned int*)d_ws;       // 16 uints (2 barriers x 4)
    float* p1g = (float*)d_ws + 16;                // 128 x 256 float2
    float* p2g = p1g + 2 * NBLK * 256;             // 128 x 128 float2
    float* out = (float*)d_out;

    hipMemsetAsync(d_ws, 0, 64, stream);           // zero barrier counters

    deepfm_one<<<NBLK, 512, 0, stream>>>(
        x, emb, wlin, blin, W1, b1, g1, be1, W2, b2, g2, be2, W3, b3,
        cnt, p1g, p2g, out);
}

// Round 6
// 48.574 us; speedup vs baseline: 3.1810x; 1.0952x over previous
//
#include <hip/hip_runtime.h>

#define EPS 1e-5f

static __device__ const int OFFS[8] = {0, 100000, 150000, 151000, 151500, 151600, 151650, 151670};

// ============================================================================
// K1: 256 blocks x 512 threads, 8 rows/block (wave = 1 row; r=t>>6, c=t&63).
// gather -> FM -> h0 (LDS) -> GEMM1 (deep-ILP, 4 cols/thread) -> z1 + partials.
// ============================================================================
__global__ __launch_bounds__(512) void k1_gather_fm_gemm1(
    const int* __restrict__ x, const float* __restrict__ emb,
    const float* __restrict__ wlin, const float* __restrict__ blin,
    const float* __restrict__ W1, const float* __restrict__ b1,
    float* __restrict__ yfm, float* __restrict__ z1, float* __restrict__ p1)
{
    __shared__ __align__(16) float h0s[8][128];
    __shared__ __align__(16) float redS[8][256];
    __shared__ __align__(16) float redQ[8][256];

    const int t = threadIdx.x, blk = blockIdx.x;
    const int r = t >> 6, c = t & 63;
    const int row = blk * 8 + r;

    // ---- gather + FM ----
    {
        const int f = c >> 3, dp = c & 7;
        const int idxf = x[row * 8 + f];
        float2 e = *(const float2*)&emb[(size_t)(idxf + OFFS[f]) * 16 + dp * 2];
        *(float2*)&h0s[r][f * 16 + dp * 2] = e;

        float sx = e.x, sy = e.y, qx = e.x * e.x, qy = e.y * e.y;
#pragma unroll
        for (int m = 8; m <= 32; m <<= 1) {           // sum over fields (bits 3..5)
            sx += __shfl_xor(sx, m); sy += __shfl_xor(sy, m);
            qx += __shfl_xor(qx, m); qy += __shfl_xor(qy, m);
        }
        float pair = (sx * sx - qx) + (sy * sy - qy);
        pair += __shfl_xor(pair, 1);                  // sum over dp (bits 0..2)
        pair += __shfl_xor(pair, 2);
        pair += __shfl_xor(pair, 4);

        float lin = 0.f;
        if (c < 8) {
            int ids[8];
#pragma unroll
            for (int g = 0; g < 8; ++g) ids[g] = x[row * 8 + g];
            bool dup = false;
            for (int g = 0; g < c; ++g) dup = dup || (ids[g] == ids[c]);
            lin = dup ? 0.f : wlin[ids[c]];
        }
        lin += __shfl_xor(lin, 1);
        lin += __shfl_xor(lin, 2);
        lin += __shfl_xor(lin, 4);
        if (c == 0) yfm[row] = 0.5f * pair + lin + blin[0];
    }
    __syncthreads();

    // ---- GEMM1: row r, cols j0..j0+3; k-chunks of 16 with 16 loads in flight
    const int j0 = c * 4;
    float a0 = 0.f, a1 = 0.f, a2 = 0.f, a3 = 0.f;
#pragma unroll
    for (int k0 = 0; k0 < 128; k0 += 16) {
        float4 h[4];
#pragma unroll
        for (int i = 0; i < 4; ++i) h[i] = *(const float4*)&h0s[r][k0 + i * 4];
        float4 w[16];
#pragma unroll
        for (int kk = 0; kk < 16; ++kk) w[kk] = *(const float4*)&W1[(size_t)(k0 + kk) * 256 + j0];
#pragma unroll
        for (int kk = 0; kk < 16; ++kk) {
            const float hv = ((const float*)h)[kk];
            a0 += hv * w[kk].x; a1 += hv * w[kk].y;
            a2 += hv * w[kk].z; a3 += hv * w[kk].w;
        }
    }
    float4 b4 = *(const float4*)&b1[j0];
    float4 zv = make_float4(a0 + b4.x, a1 + b4.y, a2 + b4.z, a3 + b4.w);
    *(float4*)&z1[(size_t)row * 256 + j0] = zv;
    *(float4*)&redS[r][j0] = zv;
    *(float4*)&redQ[r][j0] = make_float4(zv.x * zv.x, zv.y * zv.y, zv.z * zv.z, zv.w * zv.w);
    __syncthreads();
    if (t < 256) {
        float s = 0.f, q = 0.f;
#pragma unroll
        for (int rr = 0; rr < 8; ++rr) { s += redS[rr][t]; q += redQ[rr][t]; }
        *(float2*)&p1[(size_t)(blk * 256 + t) * 2] = make_float2(s, q);
    }
}

// ============================================================================
// K2: 256 blocks x 512 threads, 8 rows/block. Redundant BN1 stats (cached,
// coalesced) -> BN+ReLU -> h1 (LDS) -> GEMM2 (2 cols/thread, deep ILP) ->
// z2 + partials.
// ============================================================================
__global__ __launch_bounds__(512) void k2_bn1_gemm2(
    const float* __restrict__ z1, const float* __restrict__ p1,
    const float* __restrict__ g1, const float* __restrict__ be1,
    const float* __restrict__ W2, const float* __restrict__ b2,
    float* __restrict__ z2, float* __restrict__ p2)
{
    __shared__ __align__(16) float h1s[8][256];
    __shared__ __align__(16) float sclS[256], shfS[256];
    __shared__ __align__(16) float sbuf[2][256], qbuf[2][256];
    __shared__ __align__(16) float redS[8][128];
    __shared__ __align__(16) float redQ[8][128];

    const int t = threadIdx.x, blk = blockIdx.x;

    // ---- BN1 stats: 2 threads/col x 128 tiles each, normal cached loads
    {
        const int col = t & 255, h = t >> 8;
        float s = 0.f, q = 0.f;
#pragma unroll 16
        for (int i = 0; i < 128; ++i) {
            float2 v = *(const float2*)&p1[(size_t)((h * 128 + i) * 256 + col) * 2];
            s += v.x; q += v.y;
        }
        sbuf[h][col] = s; qbuf[h][col] = q;
    }
    __syncthreads();
    if (t < 256) {
        float s = sbuf[0][t] + sbuf[1][t];
        float q = qbuf[0][t] + qbuf[1][t];
        float mean = s * (1.f / 2048.f);
        float var  = q * (1.f / 2048.f) - mean * mean;
        float sc = g1[t] * __frsqrt_rn(var + EPS);
        sclS[t] = sc;
        shfS[t] = be1[t] - mean * sc;
    }
    __syncthreads();

    // ---- z1 -> BN+ReLU -> h1s
    {
        const int lr = t >> 6, lc = (t & 63) * 4;
        float4 zv = *(const float4*)&z1[(size_t)(blk * 8 + lr) * 256 + lc];
        float4 sc = *(const float4*)&sclS[lc];
        float4 sh = *(const float4*)&shfS[lc];
        float4 hv;
        hv.x = fmaxf(zv.x * sc.x + sh.x, 0.f);
        hv.y = fmaxf(zv.y * sc.y + sh.y, 0.f);
        hv.z = fmaxf(zv.z * sc.z + sh.z, 0.f);
        hv.w = fmaxf(zv.w * sc.w + sh.w, 0.f);
        *(float4*)&h1s[lr][lc] = hv;
    }
    __syncthreads();

    // ---- GEMM2: row r=t>>6, cols j0=(t&63)*2; k-chunks of 16
    const int r = t >> 6, j0 = (t & 63) * 2;
    float a0 = 0.f, a1 = 0.f;
#pragma unroll
    for (int k0 = 0; k0 < 256; k0 += 16) {
        float4 h[4];
#pragma unroll
        for (int i = 0; i < 4; ++i) h[i] = *(const float4*)&h1s[r][k0 + i * 4];
        float2 w[16];
#pragma unroll
        for (int kk = 0; kk < 16; ++kk) w[kk] = *(const float2*)&W2[(size_t)(k0 + kk) * 128 + j0];
#pragma unroll
        for (int kk = 0; kk < 16; ++kk) {
            const float hv = ((const float*)h)[kk];
            a0 += hv * w[kk].x; a1 += hv * w[kk].y;
        }
    }
    float2 b2v = *(const float2*)&b2[j0];
    float za = a0 + b2v.x, zb = a1 + b2v.y;
    const int row = blk * 8 + r;
    *(float2*)&z2[(size_t)row * 128 + j0] = make_float2(za, zb);
    *(float2*)&redS[r][j0] = make_float2(za, zb);
    *(float2*)&redQ[r][j0] = make_float2(za * za, zb * zb);
    __syncthreads();
    if (t < 128) {
        float s = 0.f, q = 0.f;
#pragma unroll
        for (int rr = 0; rr < 8; ++rr) { s += redS[rr][t]; q += redQ[rr][t]; }
        *(float2*)&p2[(size_t)(blk * 128 + t) * 2] = make_float2(s, q);
    }
}

// ============================================================================
// K3: 256 blocks x 256 threads, 8 rows/block. Redundant BN2 stats -> BN+ReLU
// -> dot W3 -> out (+ yfm).
// ============================================================================
__global__ __launch_bounds__(256) void k3_bn2_out(
    const float* __restrict__ z2, const float* __restrict__ p2,
    const float* __restrict__ g2, const float* __restrict__ be2,
    const float* __restrict__ W3, const float* __restrict__ b3,
    const float* __restrict__ yfm, float* __restrict__ out)
{
    __shared__ __align__(16) float sbuf[2][128], qbuf[2][128];
    __shared__ __align__(16) float scl[128], shf[128];

    const int t = threadIdx.x, blk = blockIdx.x;

    // ---- BN2 stats: 2 threads/col x 128 tiles each
    {
        const int col = t & 127, h = t >> 7;
        float s = 0.f, q = 0.f;
#pragma unroll 16
        for (int i = 0; i < 128; ++i) {
            float2 v = *(const float2*)&p2[(size_t)((h * 128 + i) * 128 + col) * 2];
            s += v.x; q += v.y;
        }
        sbuf[h][col] = s; qbuf[h][col] = q;
    }
    __syncthreads();
    if (t < 128) {
        float s = sbuf[0][t] + sbuf[1][t];
        float q = qbuf[0][t] + qbuf[1][t];
        float mean = s * (1.f / 2048.f);
        float var  = q * (1.f / 2048.f) - mean * mean;
        float sc = g2[t] * __frsqrt_rn(var + EPS);
        scl[t] = sc;
        shf[t] = be2[t] - mean * sc;
    }
    __syncthreads();

    // ---- output: 32 threads/row, 4 dims each
    const int r = t >> 5, l = t & 31;
    const int b = blk * 8 + r;
    float4 zv = *(const float4*)&z2[(size_t)b * 128 + l * 4];
    float4 sc = *(const float4*)&scl[l * 4];
    float4 sh = *(const float4*)&shf[l * 4];
    float4 wv = *(const float4*)&W3[l * 4];
    float acc = fmaxf(zv.x * sc.x + sh.x, 0.f) * wv.x
              + fmaxf(zv.y * sc.y + sh.y, 0.f) * wv.y
              + fmaxf(zv.z * sc.z + sh.z, 0.f) * wv.z
              + fmaxf(zv.w * sc.w + sh.w, 0.f) * wv.w;
#pragma unroll
    for (int m = 16; m >= 1; m >>= 1) acc += __shfl_xor(acc, m);
    if (l == 0) out[b] = acc + b3[0] + yfm[b];
}

extern "C" void kernel_launch(void* const* d_in, const int* in_sizes, int n_in,
                              void* d_out, int out_size, void* d_ws, size_t ws_size,
                              hipStream_t stream) {
    const int*   x    = (const int*)d_in[0];
    const float* emb  = (const float*)d_in[1];
    const float* wlin = (const float*)d_in[2];
    const float* blin = (const float*)d_in[3];
    const float* W1   = (const float*)d_in[4];
    const float* b1   = (const float*)d_in[5];
    const float* g1   = (const float*)d_in[6];
    const float* be1  = (const float*)d_in[7];
    const float* W2   = (const float*)d_in[8];
    const float* b2   = (const float*)d_in[9];
    const float* g2   = (const float*)d_in[10];
    const float* be2  = (const float*)d_in[11];
    const float* W3   = (const float*)d_in[12];
    const float* b3   = (const float*)d_in[13];

    float* ws  = (float*)d_ws;
    float* yfm = ws;                        // 2048
    float* z1  = yfm + 2048;                // 2048*256
    float* p1  = z1 + 2048 * 256;           // 256 tiles x 256 cols x {s,q}
    float* z2  = p1 + 2 * 256 * 256;        // 2048*128
    float* p2  = z2 + 2048 * 128;           // 256 tiles x 128 cols x {s,q}
    float* out = (float*)d_out;

    k1_gather_fm_gemm1<<<256, 512, 0, stream>>>(x, emb, wlin, blin, W1, b1, yfm, z1, p1);
    k2_bn1_gemm2<<<256, 512, 0, stream>>>(z1, p1, g1, be1, W2, b2, z2, p2);
    k3_bn2_out<<<256, 256, 0, stream>>>(z2, p2, g2, be2, W3, b3, yfm, out);
}

// Round 7
// 39.143 us; speedup vs baseline: 3.9474x; 1.2409x over previous
//
#include <hip/hip_runtime.h>

#define EPS 1e-5f

static __device__ const int OFFS[8] = {0, 100000, 150000, 151000, 151500, 151600, 151650, 151670};

// ============================================================================
// K1: 512 blocks x 256 thr. Block = (rt = blk>>1) 8 rows x (ch = blk&1) 128 cols.
// gather+FM (ch==0 writes yfm) -> h0 LDS -> GEMM1 (2r x 2c/thread, k-chunk 16)
// -> z1 + per-block col partials p1[rt][j].
// ============================================================================
__global__ __launch_bounds__(256) void k1_gather_fm_gemm1(
    const int* __restrict__ x, const float* __restrict__ emb,
    const float* __restrict__ wlin, const float* __restrict__ blin,
    const float* __restrict__ W1, const float* __restrict__ b1,
    float* __restrict__ yfm, float* __restrict__ z1, float* __restrict__ p1)
{
    __shared__ __align__(16) float h0s[8][128];
    __shared__ __align__(16) float redS[8][128];
    __shared__ __align__(16) float redQ[8][128];

    const int t = threadIdx.x;
    const int rt = blockIdx.x >> 1, ch = blockIdx.x & 1;

    // ---- gather + FM: 32 threads/row (r = t>>5), f = bits2..4, dq = bits0..1
    {
        const int r = t >> 5, c = t & 31;
        const int row = rt * 8 + r;
        const int f = c >> 2, dq = (c & 3) * 4;
        const int idxf = x[row * 8 + f];
        float4 e = *(const float4*)&emb[(size_t)(idxf + OFFS[f]) * 16 + dq];
        *(float4*)&h0s[r][f * 16 + dq] = e;

        if (ch == 0) {
            float4 s = e;
            float4 q = make_float4(e.x * e.x, e.y * e.y, e.z * e.z, e.w * e.w);
#pragma unroll
            for (int m = 4; m <= 16; m <<= 1) {        // sum over fields
                s.x += __shfl_xor(s.x, m); s.y += __shfl_xor(s.y, m);
                s.z += __shfl_xor(s.z, m); s.w += __shfl_xor(s.w, m);
                q.x += __shfl_xor(q.x, m); q.y += __shfl_xor(q.y, m);
                q.z += __shfl_xor(q.z, m); q.w += __shfl_xor(q.w, m);
            }
            float pair = (s.x * s.x - q.x) + (s.y * s.y - q.y)
                       + (s.z * s.z - q.z) + (s.w * s.w - q.w);
            pair += __shfl_xor(pair, 1);               // sum over dq lanes
            pair += __shfl_xor(pair, 2);

            float lin = 0.f;
            if (c < 8) {
                int ids[8];
#pragma unroll
                for (int g = 0; g < 8; ++g) ids[g] = x[row * 8 + g];
                bool dup = false;
                for (int g = 0; g < c; ++g) dup = dup || (ids[g] == ids[c]);
                lin = dup ? 0.f : wlin[ids[c]];
            }
            lin += __shfl_xor(lin, 1);
            lin += __shfl_xor(lin, 2);
            lin += __shfl_xor(lin, 4);
            if (c == 0) yfm[row] = 0.5f * pair + lin + blin[0];
        }
    }
    __syncthreads();

    // ---- GEMM1: thread = rows {rg*2, rg*2+1} x cols {j, j+1}; k-chunks of 16
    const int cc = t & 63, rg = t >> 6;
    const int j = ch * 128 + cc * 2;
    const int r0 = rg * 2;
    float a00 = 0.f, a01 = 0.f, a10 = 0.f, a11 = 0.f;
#pragma unroll
    for (int k0 = 0; k0 < 128; k0 += 16) {
        float4 ha[4], hb[4];
#pragma unroll
        for (int i = 0; i < 4; ++i) {
            ha[i] = *(const float4*)&h0s[r0][k0 + i * 4];
            hb[i] = *(const float4*)&h0s[r0 + 1][k0 + i * 4];
        }
        float2 w[16];
#pragma unroll
        for (int kk = 0; kk < 16; ++kk)
            w[kk] = *(const float2*)&W1[(size_t)(k0 + kk) * 256 + j];
#pragma unroll
        for (int kk = 0; kk < 16; ++kk) {
            const float hva = ((const float*)ha)[kk];
            const float hvb = ((const float*)hb)[kk];
            a00 += hva * w[kk].x; a01 += hva * w[kk].y;
            a10 += hvb * w[kk].x; a11 += hvb * w[kk].y;
        }
    }
    float2 b2v = *(const float2*)&b1[j];
    float z00 = a00 + b2v.x, z01 = a01 + b2v.y;
    float z10 = a10 + b2v.x, z11 = a11 + b2v.y;
    *(float2*)&z1[(size_t)(rt * 8 + r0) * 256 + j]     = make_float2(z00, z01);
    *(float2*)&z1[(size_t)(rt * 8 + r0 + 1) * 256 + j] = make_float2(z10, z11);
    *(float2*)&redS[r0][cc * 2]     = make_float2(z00, z01);
    *(float2*)&redS[r0 + 1][cc * 2] = make_float2(z10, z11);
    *(float2*)&redQ[r0][cc * 2]     = make_float2(z00 * z00, z01 * z01);
    *(float2*)&redQ[r0 + 1][cc * 2] = make_float2(z10 * z10, z11 * z11);
    __syncthreads();
    if (t < 128) {
        float s = 0.f, q = 0.f;
#pragma unroll
        for (int rr = 0; rr < 8; ++rr) { s += redS[rr][t]; q += redQ[rr][t]; }
        *(float2*)&p1[(size_t)(rt * 256 + ch * 128 + t) * 2] = make_float2(s, q);
    }
}

// ============================================================================
// R: reduce partials -> scale/shift. Grid = NCOLS/8 blocks x 256 thr.
// Block b owns cols b*8..b*8+7; thread (g = t>>3, cc = t&7) sums tiles
// g, g+32, ..., then wave + LDS reduce. sg[col] = scale, sg[NCOLS+col] = shift.
// ============================================================================
template <int NCOLS>
__global__ __launch_bounds__(256) void kr_stats(
    const float* __restrict__ p, const float* __restrict__ gamma,
    const float* __restrict__ beta, float* __restrict__ sg)
{
    __shared__ float partS[4][8], partQ[4][8];
    const int t = threadIdx.x, blk = blockIdx.x;
    const int cc = t & 7, g = t >> 3;
    const int col = blk * 8 + cc;

    float s = 0.f, q = 0.f;
#pragma unroll
    for (int i = 0; i < 8; ++i) {
        float2 v = *(const float2*)&p[(size_t)((g + i * 32) * NCOLS + col) * 2];
        s += v.x; q += v.y;
    }
#pragma unroll
    for (int m = 8; m <= 32; m <<= 1) {   // reduce g within wave (lane bits 3..5)
        s += __shfl_xor(s, m);
        q += __shfl_xor(q, m);
    }
    if ((t & 63) < 8) {
        partS[t >> 6][cc] = s;
        partQ[t >> 6][cc] = q;
    }
    __syncthreads();
    if (t < 8) {
        float fs = partS[0][t] + partS[1][t] + partS[2][t] + partS[3][t];
        float fq = partQ[0][t] + partQ[1][t] + partQ[2][t] + partQ[3][t];
        const int c = blk * 8 + t;
        float mean = fs * (1.f / 2048.f);
        float var  = fq * (1.f / 2048.f) - mean * mean;
        float sc = gamma[c] * __frsqrt_rn(var + EPS);
        sg[c] = sc;
        sg[NCOLS + c] = beta[c] - mean * sc;
    }
}

// ============================================================================
// K2: 256 blocks x 512 thr, 8 rows/block. scale/shift (2KB) -> BN1+ReLU ->
// h1 LDS -> GEMM2 (1r x 2c/thread, k-chunk 16) -> z2 + partials.
// ============================================================================
__global__ __launch_bounds__(512) void k2_bn1_gemm2(
    const float* __restrict__ z1, const float* __restrict__ s1g,
    const float* __restrict__ W2, const float* __restrict__ b2,
    float* __restrict__ z2, float* __restrict__ p2)
{
    __shared__ __align__(16) float h1s[8][256];
    __shared__ __align__(16) float redS[8][128];
    __shared__ __align__(16) float redQ[8][128];

    const int t = threadIdx.x, blk = blockIdx.x;

    // ---- BN1+ReLU -> h1s (512 thr x float4 = 8x256)
    {
        const int lr = t >> 6, lc = (t & 63) * 4;
        float4 zv = *(const float4*)&z1[(size_t)(blk * 8 + lr) * 256 + lc];
        float4 sc = *(const float4*)&s1g[lc];
        float4 sh = *(const float4*)&s1g[256 + lc];
        float4 hv;
        hv.x = fmaxf(zv.x * sc.x + sh.x, 0.f);
        hv.y = fmaxf(zv.y * sc.y + sh.y, 0.f);
        hv.z = fmaxf(zv.z * sc.z + sh.z, 0.f);
        hv.w = fmaxf(zv.w * sc.w + sh.w, 0.f);
        *(float4*)&h1s[lr][lc] = hv;
    }
    __syncthreads();

    // ---- GEMM2: thread = row (t>>6) x cols {j, j+1}; k-chunks of 16
    const int r = t >> 6, j = (t & 63) * 2;
    float a0 = 0.f, a1 = 0.f;
#pragma unroll
    for (int k0 = 0; k0 < 256; k0 += 16) {
        float4 h[4];
#pragma unroll
        for (int i = 0; i < 4; ++i) h[i] = *(const float4*)&h1s[r][k0 + i * 4];
        float2 w[16];
#pragma unroll
        for (int kk = 0; kk < 16; ++kk)
            w[kk] = *(const float2*)&W2[(size_t)(k0 + kk) * 128 + j];
#pragma unroll
        for (int kk = 0; kk < 16; ++kk) {
            const float hv = ((const float*)h)[kk];
            a0 += hv * w[kk].x; a1 += hv * w[kk].y;
        }
    }
    float2 bv = *(const float2*)&b2[j];
    float za = a0 + bv.x, zb = a1 + bv.y;
    *(float2*)&z2[(size_t)(blk * 8 + r) * 128 + j] = make_float2(za, zb);
    *(float2*)&redS[r][j] = make_float2(za, zb);
    *(float2*)&redQ[r][j] = make_float2(za * za, zb * zb);
    __syncthreads();
    if (t < 128) {
        float s = 0.f, q = 0.f;
#pragma unroll
        for (int rr = 0; rr < 8; ++rr) { s += redS[rr][t]; q += redQ[rr][t]; }
        *(float2*)&p2[(size_t)(blk * 128 + t) * 2] = make_float2(s, q);
    }
}

// ============================================================================
// K3: 256 blocks x 256 thr, 8 rows/block. BN2+ReLU, dot W3, + yfm -> out.
// ============================================================================
__global__ __launch_bounds__(256) void k3_bn2_out(
    const float* __restrict__ z2, const float* __restrict__ s2g,
    const float* __restrict__ W3, const float* __restrict__ b3,
    const float* __restrict__ yfm, float* __restrict__ out)
{
    const int t = threadIdx.x, blk = blockIdx.x;
    const int r = t >> 5, l = t & 31;
    const int b = blk * 8 + r;
    float4 zv = *(const float4*)&z2[(size_t)b * 128 + l * 4];
    float4 sc = *(const float4*)&s2g[l * 4];
    float4 sh = *(const float4*)&s2g[128 + l * 4];
    float4 wv = *(const float4*)&W3[l * 4];
    float acc = fmaxf(zv.x * sc.x + sh.x, 0.f) * wv.x
              + fmaxf(zv.y * sc.y + sh.y, 0.f) * wv.y
              + fmaxf(zv.z * sc.z + sh.z, 0.f) * wv.z
              + fmaxf(zv.w * sc.w + sh.w, 0.f) * wv.w;
#pragma unroll
    for (int m = 16; m >= 1; m >>= 1) acc += __shfl_xor(acc, m);
    if (l == 0) out[b] = acc + b3[0] + yfm[b];
}

extern "C" void kernel_launch(void* const* d_in, const int* in_sizes, int n_in,
                              void* d_out, int out_size, void* d_ws, size_t ws_size,
                              hipStream_t stream) {
    const int*   x    = (const int*)d_in[0];
    const float* emb  = (const float*)d_in[1];
    const float* wlin = (const float*)d_in[2];
    const float* blin = (const float*)d_in[3];
    const float* W1   = (const float*)d_in[4];
    const float* b1   = (const float*)d_in[5];
    const float* g1   = (const float*)d_in[6];
    const float* be1  = (const float*)d_in[7];
    const float* W2   = (const float*)d_in[8];
    const float* b2   = (const float*)d_in[9];
    const float* g2   = (const float*)d_in[10];
    const float* be2  = (const float*)d_in[11];
    const float* W3   = (const float*)d_in[12];
    const float* b3   = (const float*)d_in[13];

    float* ws  = (float*)d_ws;
    float* yfm = ws;                          // 2048
    float* z1  = yfm + 2048;                  // 2048*256
    float* p1  = z1 + 2048 * 256;             // 256 tiles x 256 cols x {s,q}
    float* s1g = p1 + 2 * 256 * 256;          // 512 (scale|shift)
    float* z2  = s1g + 512;                   // 2048*128
    float* p2  = z2 + 2048 * 128;             // 256 tiles x 128 cols x {s,q}
    float* s2g = p2 + 2 * 256 * 128;          // 256 (scale|shift)
    float* out = (float*)d_out;

    k1_gather_fm_gemm1<<<512, 256, 0, stream>>>(x, emb, wlin, blin, W1, b1, yfm, z1, p1);
    kr_stats<256><<<32, 256, 0, stream>>>(p1, g1, be1, s1g);
    k2_bn1_gemm2<<<256, 512, 0, stream>>>(z1, s1g, W2, b2, z2, p2);
    kr_stats<128><<<16, 256, 0, stream>>>(p2, g2, be2, s2g);
    k3_bn2_out<<<256, 256, 0, stream>>>(z2, s2g, W3, b3, yfm, out);
}